// Round 1
// baseline (267.128 us; speedup 1.0000x reference)
//
#include <hip/hip_runtime.h>

typedef _Float16 half8 __attribute__((ext_vector_type(8)));
typedef _Float16 half4 __attribute__((ext_vector_type(4)));
typedef float floatx4 __attribute__((ext_vector_type(4)));
typedef unsigned int uint4v __attribute__((ext_vector_type(4)));

#define NROW 196        // image tokens after slicing [:,1:]
#define NCOL 64         // text tokens after slicing [:,1:]
#define DIM  768
#define BK   64
#define LDA  72         // 64 + 8 f16 pad -> row stride 144 B (breaks 32-dword bank stride)
#define LDB  72
#define NRT  13         // row tiles of 16 (196 -> 208 padded)

// ---------------- f32 -> f16 slice+convert ----------------
// out[(i*RPB + r)*768 + d] = in[(i*(RPB+1) + r + 1)*768 + d]
// src flat elem = out flat elem + 768*(i+1)   (holds for both image and text)
__global__ __launch_bounds__(256) void convert_slice(const float* __restrict__ in,
                                                     _Float16* __restrict__ outh,
                                                     int rows_per_batch, int total4) {
  int idx = blockIdx.x * 256 + threadIdx.x;
  if (idx >= total4) return;
  int row = idx / 192;                 // 768/4 groups per row
  int i = row / rows_per_batch;
  size_t e = (size_t)idx * 4;
  const floatx4 v = *(const floatx4*)(in + e + (size_t)768 * (i + 1));
  half4 h;
  h[0] = (_Float16)v[0]; h[1] = (_Float16)v[1];
  h[2] = (_Float16)v[2]; h[3] = (_Float16)v[3];
  *(half4*)(outh + e) = h;
}

// ---------------- per-(i,j) similarity tile + reductions ----------------
__global__ __launch_bounds__(256, 4) void sim_kernel(const _Float16* __restrict__ imgh,
                                                     const _Float16* __restrict__ txth,
                                                     const int* __restrict__ pm,
                                                     const float* __restrict__ logit_scale,
                                                     float* __restrict__ lpi,
                                                     float* __restrict__ lpt) {
  __shared__ _Float16 Ash[208 * LDA];
  __shared__ _Float16 Bsh[64 * LDB];
  __shared__ float colmaxLDS[4][64];
  __shared__ float wsumLDS[4];

  const int j = blockIdx.x, i = blockIdx.y;
  const int tid = threadIdx.x;
  const int wave = tid >> 6, lane = tid & 63;
  const int quad = lane >> 4, r16 = lane & 15;
  // wave w owns row tiles {w, w+4, w+8, (w+12)}; wave 0 gets 4 tiles, others 3
  const int NT = (wave == 0) ? 4 : 3;

  floatx4 acc[4][4];
#pragma unroll
  for (int t = 0; t < 4; ++t)
#pragma unroll
    for (int ct = 0; ct < 4; ++ct)
      acc[t][ct] = (floatx4){0.f, 0.f, 0.f, 0.f};

  // zero the pad rows 196..207 once (never rewritten)
  if (tid < 96) {
    int row = 196 + (tid >> 3), cg = tid & 7;
    *(uint4v*)(&Ash[row * LDA + cg * 8]) = (uint4v){0u, 0u, 0u, 0u};
  }

  const _Float16* Abase = imgh + (size_t)i * NROW * DIM;
  const _Float16* Bbase = txth + (size_t)j * NCOL * DIM;

  for (int kk = 0; kk < DIM; kk += BK) {
    // stage A: 196 rows x 64 cols = 1568 16B slots
#pragma unroll
    for (int t = 0; t < 7; ++t) {
      int l = tid + 256 * t;
      if (l < 1568) {
        int row = l >> 3, cg = l & 7;
        uint4v v = *(const uint4v*)(Abase + (size_t)row * DIM + kk + cg * 8);
        *(uint4v*)(&Ash[row * LDA + cg * 8]) = v;
      }
    }
    // stage B: 64 rows x 64 cols = 512 slots
#pragma unroll
    for (int t = 0; t < 2; ++t) {
      int l = tid + 256 * t;
      int row = l >> 3, cg = l & 7;
      uint4v v = *(const uint4v*)(Bbase + (size_t)row * DIM + kk + cg * 8);
      *(uint4v*)(&Bsh[row * LDB + cg * 8]) = v;
    }
    __syncthreads();

#pragma unroll
    for (int ks = 0; ks < BK; ks += 32) {
      half8 bfrag[4];
#pragma unroll
      for (int ct = 0; ct < 4; ++ct)
        bfrag[ct] = *(const half8*)(&Bsh[(ct * 16 + r16) * LDB + ks + quad * 8]);
#pragma unroll
      for (int t = 0; t < 4; ++t) {
        if (t < NT) {
          int rt = wave + 4 * t;
          half8 afrag = *(const half8*)(&Ash[(rt * 16 + r16) * LDA + ks + quad * 8]);
#pragma unroll
          for (int ct = 0; ct < 4; ++ct)
            acc[t][ct] = __builtin_amdgcn_mfma_f32_16x16x32_f16(afrag, bfrag[ct], acc[t][ct], 0, 0, 0);
        }
      }
    }
    __syncthreads();
  }

  // ---------------- epilogue ----------------
  const float s = logit_scale[0];
  // mask (reference broadcasts pm over i, NOT j): col m masked iff pm[i, m+1] != 0
  bool maskc[4];
#pragma unroll
  for (int ct = 0; ct < 4; ++ct)
    maskc[ct] = pm[i * 65 + 1 + ct * 16 + r16] != 0;

  // ---- logits_per_image: mean_n of max over valid m ----
  float rowsum = 0.f;
#pragma unroll
  for (int t = 0; t < 4; ++t) {
    if (t < NT) {
      int rt = wave + 4 * t;
#pragma unroll
      for (int r = 0; r < 4; ++r) {
        int row = rt * 16 + quad * 4 + r;   // C/D layout: row = quad*4 + reg (m89/m91)
        float rm = -__builtin_inff();
#pragma unroll
        for (int ct = 0; ct < 4; ++ct) {
          float v = acc[t][ct][r] * s;
          rm = fmaxf(rm, maskc[ct] ? -__builtin_inff() : v);
        }
#pragma unroll
        for (int off = 1; off < 16; off <<= 1)
          rm = fmaxf(rm, __shfl_xor(rm, off, 64));
        if (row < NROW) rowsum += rm;       // each row counted 16x (all r16 lanes)
      }
    }
  }
#pragma unroll
  for (int off = 1; off < 64; off <<= 1) rowsum += __shfl_xor(rowsum, off, 64);
  if (lane == 0) wsumLDS[wave] = rowsum;

  // ---- logits_per_text: masked mean over m of max over n (exclude pad rows!) ----
  float cm[4];
#pragma unroll
  for (int ct = 0; ct < 4; ++ct) {
    cm[ct] = -__builtin_inff();
#pragma unroll
    for (int t = 0; t < 4; ++t) {
      if (t < NT) {
        int rt = wave + 4 * t;
#pragma unroll
        for (int r = 0; r < 4; ++r) {
          int row = rt * 16 + quad * 4 + r;
          if (row < NROW) cm[ct] = fmaxf(cm[ct], acc[t][ct][r] * s);
        }
      }
    }
    cm[ct] = fmaxf(cm[ct], __shfl_xor(cm[ct], 16, 64));
    cm[ct] = fmaxf(cm[ct], __shfl_xor(cm[ct], 32, 64));
  }
  if (lane < 16) {
#pragma unroll
    for (int ct = 0; ct < 4; ++ct) colmaxLDS[wave][ct * 16 + lane] = cm[ct];
  }
  __syncthreads();

  if (tid == 0) {
    float total = wsumLDS[0] + wsumLDS[1] + wsumLDS[2] + wsumLDS[3];
    lpi[i * 64 + j] = total / (16.f * (float)NROW);
  }
  if (tid < 64) {   // exactly wave 0
    int col = tid;
    float v = fmaxf(fmaxf(colmaxLDS[0][col], colmaxLDS[1][col]),
                    fmaxf(colmaxLDS[2][col], colmaxLDS[3][col]));
    bool valid = pm[i * 65 + 1 + col] == 0;
    float contrib = valid ? v : 0.f;
    float cntv = valid ? 1.f : 0.f;
#pragma unroll
    for (int off = 1; off < 64; off <<= 1) {
      contrib += __shfl_xor(contrib, off, 64);
      cntv += __shfl_xor(cntv, off, 64);
    }
    if (tid == 0) lpt[i * 64 + j] = contrib / cntv;
  }
}

// ---------------- CE losses + targets ----------------
// out layout: [0] loss | [1..4097) lpi | [4097..8193) lpt | [8193..8257) targets
__global__ __launch_bounds__(64) void ce_kernel(float* __restrict__ out) {
  const int t = threadIdx.x;  // 64 threads = 1 wave, thread t handles row t
  const float* lpi = out + 1;
  const float* lpt = out + 1 + 4096;

  float mx = -__builtin_inff();
  for (int jj = 0; jj < 64; ++jj) mx = fmaxf(mx, lpi[t * 64 + jj]);
  float se = 0.f;
  for (int jj = 0; jj < 64; ++jj) se += __expf(lpi[t * 64 + jj] - mx);
  float ci = (mx + __logf(se)) - lpi[t * 64 + t];

  float mx2 = -__builtin_inff();
  for (int jj = 0; jj < 64; ++jj) mx2 = fmaxf(mx2, lpt[t * 64 + jj]);
  float se2 = 0.f;
  for (int jj = 0; jj < 64; ++jj) se2 += __expf(lpt[t * 64 + jj] - mx2);
  float ct_ = (mx2 + __logf(se2)) - lpt[t * 64 + t];

  float v = ci + ct_;
#pragma unroll
  for (int off = 1; off < 64; off <<= 1) v += __shfl_xor(v, off, 64);
  if (t == 0) out[0] = 0.5f * v / 64.f;
  out[1 + 8192 + t] = (float)t;   // targets = arange(64), stored as f32 values
}

extern "C" void kernel_launch(void* const* d_in, const int* in_sizes, int n_in,
                              void* d_out, int out_size, void* d_ws, size_t ws_size,
                              hipStream_t stream) {
  const float* image = (const float*)d_in[0];   // (64,197,768) f32
  const float* text  = (const float*)d_in[1];   // (64,65,768) f32
  const int*   pm    = (const int*)d_in[2];     // (64,65) i32
  const float* ls    = (const float*)d_in[3];   // scalar
  float* out = (float*)d_out;

  _Float16* imgh = (_Float16*)d_ws;                       // 64*196*768 f16
  _Float16* txth = imgh + (size_t)64 * NROW * DIM;        // 64*64*768 f16

  const int img4 = 64 * NROW * DIM / 4;   // 2,408,448
  const int txt4 = 64 * NCOL * DIM / 4;   //   786,432
  convert_slice<<<(img4 + 255) / 256, 256, 0, stream>>>(image, imgh, NROW, img4);
  convert_slice<<<(txt4 + 255) / 256, 256, 0, stream>>>(text, txth, NCOL, txt4);

  dim3 grid(64, 64);   // x = j (fast) so img[i] is L2-resident across j
  sim_kernel<<<grid, 256, 0, stream>>>(imgh, txth, pm, ls, out + 1, out + 1 + 4096);
  ce_kernel<<<1, 64, 0, stream>>>(out);
}